// Round 7
// baseline (511.259 us; speedup 1.0000x reference)
//
#include <hip/hip_runtime.h>
#include <math.h>

#define D 256
#define SCAN_CHUNK 1024
#define GPITCH 264   // bf16 LDS row pitch (pad 8) — conflict-free MFMA A-reads (r3-r5)

typedef __attribute__((ext_vector_type(8))) short frag_ab;   // 8 bf16
typedef __attribute__((ext_vector_type(4))) float frag_cd;   // 4 fp32

__device__ inline unsigned short f2b(float f) {
    unsigned int u = __float_as_uint(f);
    u += 0x7fffu + ((u >> 16) & 1u);
    return (unsigned short)(u >> 16);
}
__device__ inline float b2f(unsigned short h) {
    return __uint_as_float(((unsigned int)h) << 16);
}
// elementwise product of two packed bf16 pairs -> packed bf16 pair
__device__ inline unsigned int bmul2(unsigned int a, unsigned int b) {
    float p0 = b2f((unsigned short)(a & 0xffffu)) * b2f((unsigned short)(b & 0xffffu));
    float p1 = b2f((unsigned short)(a >> 16))     * b2f((unsigned short)(b >> 16));
    return (unsigned int)f2b(p0) | ((unsigned int)f2b(p1) << 16);
}

// ---------- zero int buffer ----------
__global__ void k_zero_int(int* p, int n) {
    int i = blockIdx.x * 256 + threadIdx.x;
    if (i < n) p[i] = 0;
}

// ---------- int degree count ----------
__global__ void k_count_int(const int* __restrict__ row, int* deg, int E) {
    int e = blockIdx.x * 256 + threadIdx.x;
    if (e < E) atomicAdd(&deg[row[e]], 1);
}

// ---------- prefix scan (3 stages); excl written into rowptr ----------
__global__ __launch_bounds__(256) void k_scan_block(const int* __restrict__ deg, int* __restrict__ excl,
                                                    int* __restrict__ bsums, int n) {
    __shared__ int s[256];
    int blk = blockIdx.x, t = threadIdx.x;
    int base = blk * SCAN_CHUNK + t * 4;
    int v0 = (base + 0 < n) ? deg[base + 0] : 0;
    int v1 = (base + 1 < n) ? deg[base + 1] : 0;
    int v2 = (base + 2 < n) ? deg[base + 2] : 0;
    int v3 = (base + 3 < n) ? deg[base + 3] : 0;
    int tsum = v0 + v1 + v2 + v3;
    s[t] = tsum;
    __syncthreads();
    for (int off = 1; off < 256; off <<= 1) {
        int x = (t >= off) ? s[t - off] : 0;
        __syncthreads();
        s[t] += x;
        __syncthreads();
    }
    int run = s[t] - tsum;
    if (t == 255) bsums[blk] = s[255];
    if (base + 0 < n) excl[base + 0] = run;
    run += v0;
    if (base + 1 < n) excl[base + 1] = run;
    run += v1;
    if (base + 2 < n) excl[base + 2] = run;
    run += v2;
    if (base + 3 < n) excl[base + 3] = run;
}

__global__ __launch_bounds__(256) void k_scan_bsums(int* bsums, int nb) {
    __shared__ int s[256];
    int t = threadIdx.x;
    int v = (t < nb) ? bsums[t] : 0;
    s[t] = v;
    __syncthreads();
    for (int off = 1; off < 256; off <<= 1) {
        int x = (t >= off) ? s[t - off] : 0;
        __syncthreads();
        s[t] += x;
        __syncthreads();
    }
    if (t < nb) bsums[t] = s[t] - v;
}

__global__ void k_scan_add(int* __restrict__ rowptr, const int* __restrict__ bsums, int n, int total) {
    int i = blockIdx.x * 256 + threadIdx.x;
    if (i < n) rowptr[i] += bsums[i / SCAN_CHUNK];
    if (i == 0) rowptr[n] = total;
}

// ---------- dinv = (deg+1)^-1/2 ----------
__global__ void k_dinv(const int* __restrict__ deg, float* __restrict__ dinv, int n) {
    int i = blockIdx.x * 256 + threadIdx.x;
    if (i < n) dinv[i] = rsqrtf((float)(deg[i] + 1));
}

// ---------- bucket edges into CSR ----------
__global__ void k_bucket(const int* __restrict__ row, const int* __restrict__ col,
                         const int* __restrict__ rowptr, int* __restrict__ fill,
                         int* __restrict__ ebuf, int E) {
    int e = blockIdx.x * 256 + threadIdx.x;
    if (e >= E) return;
    int r = row[e];
    int pos = atomicAdd(&fill[r], 1);
    ebuf[rowptr[r] + pos] = col[e];
}

// ---------- pack fp32 [k][n] weight into MFMA B-fragment order (bf16) ----------
__global__ void k_packB(const float* __restrict__ W, unsigned short* __restrict__ Bp) {
    int i = blockIdx.x * 256 + threadIdx.x;   // 65536 total
    int ntile = i >> 12;
    int kt = (i >> 9) & 7;
    int lane = (i >> 3) & 63;
    int j = i & 7;
    int k = kt * 32 + (lane >> 4) * 8 + j;
    int n = ntile * 16 + (lane & 15);
    Bp[i] = f2b(W[k * D + n]);
}

// ---------- MFMA GEMM: H16[nrows,256] = X[nrows,256] @ W  (bf16 in/out, fp32 acc) ----------
__global__ __launch_bounds__(256) void k_gemm_mfma(const void* __restrict__ X, int xIsF32,
                                                   const unsigned short* __restrict__ Bpack,
                                                   unsigned short* __restrict__ H, int nrows) {
    __shared__ unsigned short As[32 * GPITCH];
    int t = threadIdx.x;
    int rowBase = blockIdx.x * 32;

    {
        int half = t >> 7;
        int cpair = t & 127;
        for (int qi = 0; qi < 32; qi += 2) {
            int q = qi + half;
            int r = rowBase + q;
            unsigned int val = 0;
            if (r < nrows) {
                if (xIsF32) {
                    const float* xr = (const float*)X + (size_t)r * D + cpair * 2;
                    val = (unsigned int)f2b(xr[0]) | ((unsigned int)f2b(xr[1]) << 16);
                } else {
                    val = ((const unsigned int*)((const unsigned short*)X + (size_t)r * D))[cpair];
                }
            }
            *(unsigned int*)&As[q * GPITCH + cpair * 2] = val;
        }
    }
    __syncthreads();

    int w = t >> 6, lane = t & 63;
    int mtile = w >> 1;
    int nhalf = w & 1;
    int quad = lane >> 4, lcol = lane & 15;

    frag_cd acc[8];
    #pragma unroll
    for (int n = 0; n < 8; ++n) acc[n] = (frag_cd){0.f, 0.f, 0.f, 0.f};

    const frag_ab* bp = (const frag_ab*)Bpack;
    for (int kt = 0; kt < 8; ++kt) {
        frag_ab a = *(const frag_ab*)&As[(mtile * 16 + lcol) * GPITCH + kt * 32 + quad * 8];
        #pragma unroll
        for (int n = 0; n < 8; ++n) {
            frag_ab b = bp[((nhalf * 8 + n) * 8 + kt) * 64 + lane];
            acc[n] = __builtin_amdgcn_mfma_f32_16x16x32_bf16(a, b, acc[n], 0, 0, 0);
        }
    }

    #pragma unroll
    for (int n = 0; n < 8; ++n) {
        int col = (nhalf * 8 + n) * 16 + lcol;
        #pragma unroll
        for (int r = 0; r < 4; ++r) {
            int row = rowBase + mtile * 16 + quad * 4 + r;
            if (row < nrows) H[(size_t)row * D + col] = f2b(acc[n][r]);
        }
    }
}

// ---------- aggregate by gather (bf16 rows): one wave per destination node ----------
__device__ inline void acc_row(const unsigned short* Hh, int c, float nw, int c4,
                               float& a0, float& a1, float& a2, float& a3) {
    uint2 p = *(const uint2*)&Hh[(size_t)c * D + c4];
    a0 = fmaf(b2f((unsigned short)(p.x & 0xffffu)), nw, a0);
    a1 = fmaf(b2f((unsigned short)(p.x >> 16)),     nw, a1);
    a2 = fmaf(b2f((unsigned short)(p.y & 0xffffu)), nw, a2);
    a3 = fmaf(b2f((unsigned short)(p.y >> 16)),     nw, a3);
}

__global__ __launch_bounds__(256) void k_agg(const unsigned short* __restrict__ Hh,
                                             const int* __restrict__ rowptr, const int* __restrict__ ebuf,
                                             const float* __restrict__ dinv, const float* __restrict__ b,
                                             unsigned short* __restrict__ Xo, int n, int relu) {
    int node = blockIdx.x * 4 + (threadIdx.x >> 6);
    if (node >= n) return;
    int lane = threadIdx.x & 63;
    int c4 = lane * 4;

    float dn = dinv[node];
    float self = dn * dn;

    uint2 hp = *(const uint2*)&Hh[(size_t)node * D + c4];
    float4 bb = *(const float4*)&b[c4];
    float a0 = fmaf(b2f((unsigned short)(hp.x & 0xffffu)), self, bb.x);
    float a1 = fmaf(b2f((unsigned short)(hp.x >> 16)),     self, bb.y);
    float a2 = fmaf(b2f((unsigned short)(hp.y & 0xffffu)), self, bb.z);
    float a3 = fmaf(b2f((unsigned short)(hp.y >> 16)),     self, bb.w);

    int beg = rowptr[node], end = rowptr[node + 1];
    int j = beg;
    for (; j + 3 < end; j += 4) {
        int cA = ebuf[j], cB = ebuf[j + 1], cC = ebuf[j + 2], cD = ebuf[j + 3];
        float nA = dn * dinv[cA], nB = dn * dinv[cB], nC = dn * dinv[cC], nD = dn * dinv[cD];
        acc_row(Hh, cA, nA, c4, a0, a1, a2, a3);
        acc_row(Hh, cB, nB, c4, a0, a1, a2, a3);
        acc_row(Hh, cC, nC, c4, a0, a1, a2, a3);
        acc_row(Hh, cD, nD, c4, a0, a1, a2, a3);
    }
    for (; j < end; ++j) {
        int cA = ebuf[j];
        acc_row(Hh, cA, dn * dinv[cA], c4, a0, a1, a2, a3);
    }
    if (relu) {
        a0 = fmaxf(a0, 0.f); a1 = fmaxf(a1, 0.f);
        a2 = fmaxf(a2, 0.f); a3 = fmaxf(a3, 0.f);
    }
    uint2 pk;
    pk.x = (unsigned int)f2b(a0) | ((unsigned int)f2b(a1) << 16);
    pk.y = (unsigned int)f2b(a2) | ((unsigned int)f2b(a3) << 16);
    *(uint2*)&Xo[(size_t)node * D + c4] = pk;
}

// ---------- link predictor: 64 queries/block, register-direct A-frags, no staging LDS ----------
// wave w owns ntiles w*4..w*4+3 (B read ONCE per block) and all 4 mtiles (64 queries).
// A-frag for lane (quad,lcol), mtile m, ktile kt = u_row[kt*32+quad*8 ..+7] * v_row[same]
// loaded directly from global (16B each) and multiplied in registers.
__global__ __launch_bounds__(256) void k_linkpred(const int* __restrict__ u, const int* __restrict__ v,
                                                  const unsigned short* __restrict__ X16,
                                                  const unsigned short* __restrict__ Bpack,
                                                  const float* __restrict__ P1b,
                                                  const float* __restrict__ P2w, const float* __restrict__ P2b,
                                                  float* __restrict__ out, int Q) {
    __shared__ float red[4][64];

    int t = threadIdx.x;
    int w = t >> 6, lane = t & 63;
    int quad = lane >> 4, lcol = lane & 15;
    int q0 = blockIdx.x * 64;

    // per-lane endpoint row pointers for the 4 mtiles this lane touches
    const unsigned short* rowu[4];
    const unsigned short* rowv[4];
    #pragma unroll
    for (int m = 0; m < 4; ++m) {
        int qq = q0 + m * 16 + lcol;
        int qc = (qq < Q) ? qq : (Q - 1);
        rowu[m] = X16 + (size_t)u[qc] * D;
        rowv[m] = X16 + (size_t)v[qc] * D;
    }

    // per-lane epilogue constants for this wave's 4 ntiles
    float bb[4], pw[4];
    #pragma unroll
    for (int jn = 0; jn < 4; ++jn) {
        int col = (w * 4 + jn) * 16 + lcol;
        bb[jn] = P1b[col];
        pw[jn] = P2w[col];
    }

    frag_cd acc[4][4];
    #pragma unroll
    for (int m = 0; m < 4; ++m)
        #pragma unroll
        for (int jn = 0; jn < 4; ++jn) acc[m][jn] = (frag_cd){0.f, 0.f, 0.f, 0.f};

    const frag_ab* bp = (const frag_ab*)Bpack;
    #pragma unroll
    for (int kt = 0; kt < 8; ++kt) {
        int ko = kt * 32 + quad * 8;
        // build 4 A-frags in registers
        union { frag_ab f; uint4 q; } a[4];
        #pragma unroll
        for (int m = 0; m < 4; ++m) {
            uint4 au = *(const uint4*)(rowu[m] + ko);
            uint4 av = *(const uint4*)(rowv[m] + ko);
            a[m].q.x = bmul2(au.x, av.x);
            a[m].q.y = bmul2(au.y, av.y);
            a[m].q.z = bmul2(au.z, av.z);
            a[m].q.w = bmul2(au.w, av.w);
        }
        #pragma unroll
        for (int jn = 0; jn < 4; ++jn) {
            frag_ab b = bp[((w * 4 + jn) * 8 + kt) * 64 + lane];
            #pragma unroll
            for (int m = 0; m < 4; ++m)
                acc[m][jn] = __builtin_amdgcn_mfma_f32_16x16x32_bf16(a[m].f, b, acc[m][jn], 0, 0, 0);
        }
    }

    // epilogue: relu(H + b1) . P2w partials over this wave's 4 ntiles
    #pragma unroll
    for (int m = 0; m < 4; ++m) {
        float part[4] = {0.f, 0.f, 0.f, 0.f};
        #pragma unroll
        for (int jn = 0; jn < 4; ++jn)
            #pragma unroll
            for (int r = 0; r < 4; ++r)
                part[r] = fmaf(fmaxf(acc[m][jn][r] + bb[jn], 0.f), pw[jn], part[r]);
        #pragma unroll
        for (int r = 0; r < 4; ++r) {
            float s = part[r];
            s += __shfl_down(s, 8);
            s += __shfl_down(s, 4);
            s += __shfl_down(s, 2);
            s += __shfl_down(s, 1);
            if (lcol == 0) red[w][m * 16 + quad * 4 + r] = s;
        }
    }
    __syncthreads();

    if (t < 64) {
        int qq = q0 + t;
        if (qq < Q) {
            float s = red[0][t] + red[1][t] + red[2][t] + red[3][t] + P2b[0];
            out[qq] = 1.0f / (1.0f + expf(-s));
        }
    }
}

extern "C" void kernel_launch(void* const* d_in, const int* in_sizes, int n_in,
                              void* d_out, int out_size, void* d_ws, size_t ws_size,
                              hipStream_t stream) {
    const int*   edge_index = (const int*)d_in[0];
    const int*   edges      = (const int*)d_in[1];
    const float* emb        = (const float*)d_in[2];
    const float* W1         = (const float*)d_in[3];
    const float* b1         = (const float*)d_in[4];
    const float* W2         = (const float*)d_in[5];
    const float* b2         = (const float*)d_in[6];
    const float* P1w        = (const float*)d_in[7];
    const float* P1b        = (const float*)d_in[8];
    const float* P2w        = (const float*)d_in[9];
    const float* P2b        = (const float*)d_in[10];

    int E  = in_sizes[0] / 2;
    int Q  = in_sizes[1] / 2;
    int Nn = in_sizes[2] / D;

    const int* rowp = edge_index;
    const int* colp = edge_index + E;
    const int* uq   = edges;
    const int* vq   = edges + Q;
    float* out = (float*)d_out;

    // ---- workspace layout ----
    char* ws = (char*)d_ws;
    size_t off = 0;
    auto alloc = [&](size_t bytes) -> char* {
        char* p = ws + off;
        off = (off + bytes + 255) & ~(size_t)255;
        return p;
    };
    float*          dinv   = (float*)alloc((size_t)Nn * 4);
    int*            rowptr = (int*)  alloc(((size_t)Nn + 1) * 4);
    int*            ebuf   = (int*)  alloc((size_t)E * 4);
    unsigned short* BpW1   = (unsigned short*)alloc(65536 * 2);
    unsigned short* BpW2   = (unsigned short*)alloc(65536 * 2);
    unsigned short* BpP1   = (unsigned short*)alloc(65536 * 2);
    unsigned short* hbuf   = (unsigned short*)alloc((size_t)Nn * D * 2);  // bf16
    unsigned short* xbuf   = (unsigned short*)alloc((size_t)Nn * D * 2);  // bf16

    // CSR temporaries aliased into xbuf (dead until first k_agg writes it)
    int* degi  = (int*)xbuf;
    int* fill  = degi + Nn;
    int* bsums = degi + 2 * Nn;

    int nb;
    int nscan = (Nn + SCAN_CHUNK - 1) / SCAN_CHUNK;

    // CSR build
    nb = (2 * Nn + 255) / 256; k_zero_int<<<nb, 256, 0, stream>>>(degi, 2 * Nn);
    nb = (E + 255) / 256;      k_count_int<<<nb, 256, 0, stream>>>(rowp, degi, E);
    k_scan_block<<<nscan, 256, 0, stream>>>(degi, rowptr, bsums, Nn);
    k_scan_bsums<<<1, 256, 0, stream>>>(bsums, nscan);
    nb = (Nn + 255) / 256;     k_scan_add<<<nb, 256, 0, stream>>>(rowptr, bsums, Nn, E);
    nb = (Nn + 255) / 256;     k_dinv<<<nb, 256, 0, stream>>>(degi, dinv, Nn);
    nb = (E + 255) / 256;      k_bucket<<<nb, 256, 0, stream>>>(rowp, colp, rowptr, fill, ebuf, E);

    // pack weights for MFMA B operand
    k_packB<<<256, 256, 0, stream>>>(W1, BpW1);
    k_packB<<<256, 256, 0, stream>>>(W2, BpW2);
    k_packB<<<256, 256, 0, stream>>>(P1w, BpP1);

    // conv1: h = emb @ W1 (MFMA, fp32 A) ; x1 = relu(norm-agg(h) + b1)  [bf16]
    nb = (Nn + 31) / 32; k_gemm_mfma<<<nb, 256, 0, stream>>>((const void*)emb, 1, BpW1, hbuf, Nn);
    nb = (Nn + 3) / 4;   k_agg<<<nb, 256, 0, stream>>>(hbuf, rowptr, ebuf, dinv, b1, xbuf, Nn, 1);

    // conv2: h = x1 @ W2 (MFMA, bf16 A) ; x2 = norm-agg(h) + b2          [bf16]
    nb = (Nn + 31) / 32; k_gemm_mfma<<<nb, 256, 0, stream>>>((const void*)xbuf, 0, BpW2, hbuf, Nn);
    nb = (Nn + 3) / 4;   k_agg<<<nb, 256, 0, stream>>>(hbuf, rowptr, ebuf, dinv, b2, xbuf, Nn, 0);

    // link predictor (register-direct MFMA bf16, 64 q/block)
    nb = (Q + 63) / 64;  k_linkpred<<<nb, 256, 0, stream>>>(uq, vq, xbuf, BpP1, P1b, P2w, P2b, out, Q);
}

// Round 8
// 465.885 us; speedup vs baseline: 1.0974x; 1.0974x over previous
//
#include <hip/hip_runtime.h>
#include <math.h>

#define D 256
#define SCAN_CHUNK 1024
#define GPITCH 264    // bf16 LDS pitch for gemm A tiles (pad 8) — 0 conflicts measured r3/r4
#define UVPITCH 520   // bf16 pitch per query region: 256 u | 256 v | 8 pad (dword stride 260 ≡ 4 mod 32)

typedef __attribute__((ext_vector_type(8))) short frag_ab;   // 8 bf16
typedef __attribute__((ext_vector_type(4))) float frag_cd;   // 4 fp32

__device__ inline unsigned short f2b(float f) {
    unsigned int u = __float_as_uint(f);
    u += 0x7fffu + ((u >> 16) & 1u);
    return (unsigned short)(u >> 16);
}
__device__ inline float b2f(unsigned short h) {
    return __uint_as_float(((unsigned int)h) << 16);
}
// elementwise product of two packed bf16 pairs -> packed bf16 pair
__device__ inline unsigned int bmul2(unsigned int a, unsigned int b) {
    float p0 = b2f((unsigned short)(a & 0xffffu)) * b2f((unsigned short)(b & 0xffffu));
    float p1 = b2f((unsigned short)(a >> 16))     * b2f((unsigned short)(b >> 16));
    return (unsigned int)f2b(p0) | ((unsigned int)f2b(p1) << 16);
}

// async global->LDS, 16B per lane; LDS dest = wave-uniform base + lane*16
__device__ inline void async_ld16(const void* g, void* l) {
    __builtin_amdgcn_global_load_lds(
        (const __attribute__((address_space(1))) void*)g,
        (__attribute__((address_space(3))) void*)l,
        16, 0, 0);
}

// ---------- zero int buffer ----------
__global__ void k_zero_int(int* p, int n) {
    int i = blockIdx.x * 256 + threadIdx.x;
    if (i < n) p[i] = 0;
}

// ---------- int degree count ----------
__global__ void k_count_int(const int* __restrict__ row, int* deg, int E) {
    int e = blockIdx.x * 256 + threadIdx.x;
    if (e < E) atomicAdd(&deg[row[e]], 1);
}

// ---------- prefix scan (3 stages); excl written into rowptr ----------
__global__ __launch_bounds__(256) void k_scan_block(const int* __restrict__ deg, int* __restrict__ excl,
                                                    int* __restrict__ bsums, int n) {
    __shared__ int s[256];
    int blk = blockIdx.x, t = threadIdx.x;
    int base = blk * SCAN_CHUNK + t * 4;
    int v0 = (base + 0 < n) ? deg[base + 0] : 0;
    int v1 = (base + 1 < n) ? deg[base + 1] : 0;
    int v2 = (base + 2 < n) ? deg[base + 2] : 0;
    int v3 = (base + 3 < n) ? deg[base + 3] : 0;
    int tsum = v0 + v1 + v2 + v3;
    s[t] = tsum;
    __syncthreads();
    for (int off = 1; off < 256; off <<= 1) {
        int x = (t >= off) ? s[t - off] : 0;
        __syncthreads();
        s[t] += x;
        __syncthreads();
    }
    int run = s[t] - tsum;
    if (t == 255) bsums[blk] = s[255];
    if (base + 0 < n) excl[base + 0] = run;
    run += v0;
    if (base + 1 < n) excl[base + 1] = run;
    run += v1;
    if (base + 2 < n) excl[base + 2] = run;
    run += v2;
    if (base + 3 < n) excl[base + 3] = run;
}

__global__ __launch_bounds__(256) void k_scan_bsums(int* bsums, int nb) {
    __shared__ int s[256];
    int t = threadIdx.x;
    int v = (t < nb) ? bsums[t] : 0;
    s[t] = v;
    __syncthreads();
    for (int off = 1; off < 256; off <<= 1) {
        int x = (t >= off) ? s[t - off] : 0;
        __syncthreads();
        s[t] += x;
        __syncthreads();
    }
    if (t < nb) bsums[t] = s[t] - v;
}

__global__ void k_scan_add(int* __restrict__ rowptr, const int* __restrict__ bsums, int n, int total) {
    int i = blockIdx.x * 256 + threadIdx.x;
    if (i < n) rowptr[i] += bsums[i / SCAN_CHUNK];
    if (i == 0) rowptr[n] = total;
}

// ---------- dinv = (deg+1)^-1/2 ----------
__global__ void k_dinv(const int* __restrict__ deg, float* __restrict__ dinv, int n) {
    int i = blockIdx.x * 256 + threadIdx.x;
    if (i < n) dinv[i] = rsqrtf((float)(deg[i] + 1));
}

// ---------- bucket edges into CSR ----------
__global__ void k_bucket(const int* __restrict__ row, const int* __restrict__ col,
                         const int* __restrict__ rowptr, int* __restrict__ fill,
                         int* __restrict__ ebuf, int E) {
    int e = blockIdx.x * 256 + threadIdx.x;
    if (e >= E) return;
    int r = row[e];
    int pos = atomicAdd(&fill[r], 1);
    ebuf[rowptr[r] + pos] = col[e];
}

// ---------- pack fp32 [k][n] weight into MFMA B-fragment order (bf16) ----------
__global__ void k_packB(const float* __restrict__ W, unsigned short* __restrict__ Bp) {
    int i = blockIdx.x * 256 + threadIdx.x;   // 65536 total
    int ntile = i >> 12;
    int kt = (i >> 9) & 7;
    int lane = (i >> 3) & 63;
    int j = i & 7;
    int k = kt * 32 + (lane >> 4) * 8 + j;
    int n = ntile * 16 + (lane & 15);
    Bp[i] = f2b(W[k * D + n]);
}

// ---------- MFMA GEMM: H16[nrows,256] = X[nrows,256] @ W  (bf16 in/out, fp32 acc) ----------
__global__ __launch_bounds__(256) void k_gemm_mfma(const void* __restrict__ X, int xIsF32,
                                                   const unsigned short* __restrict__ Bpack,
                                                   unsigned short* __restrict__ H, int nrows) {
    __shared__ unsigned short As[32 * GPITCH];
    int t = threadIdx.x;
    int rowBase = blockIdx.x * 32;

    {
        int half = t >> 7;
        int cpair = t & 127;
        for (int qi = 0; qi < 32; qi += 2) {
            int q = qi + half;
            int r = rowBase + q;
            unsigned int val = 0;
            if (r < nrows) {
                if (xIsF32) {
                    const float* xr = (const float*)X + (size_t)r * D + cpair * 2;
                    val = (unsigned int)f2b(xr[0]) | ((unsigned int)f2b(xr[1]) << 16);
                } else {
                    val = ((const unsigned int*)((const unsigned short*)X + (size_t)r * D))[cpair];
                }
            }
            *(unsigned int*)&As[q * GPITCH + cpair * 2] = val;
        }
    }
    __syncthreads();

    int w = t >> 6, lane = t & 63;
    int mtile = w >> 1;
    int nhalf = w & 1;
    int quad = lane >> 4, lcol = lane & 15;

    frag_cd acc[8];
    #pragma unroll
    for (int n = 0; n < 8; ++n) acc[n] = (frag_cd){0.f, 0.f, 0.f, 0.f};

    const frag_ab* bp = (const frag_ab*)Bpack;
    for (int kt = 0; kt < 8; ++kt) {
        frag_ab a = *(const frag_ab*)&As[(mtile * 16 + lcol) * GPITCH + kt * 32 + quad * 8];
        #pragma unroll
        for (int n = 0; n < 8; ++n) {
            frag_ab b = bp[((nhalf * 8 + n) * 8 + kt) * 64 + lane];
            acc[n] = __builtin_amdgcn_mfma_f32_16x16x32_bf16(a, b, acc[n], 0, 0, 0);
        }
    }

    #pragma unroll
    for (int n = 0; n < 8; ++n) {
        int col = (nhalf * 8 + n) * 16 + lcol;
        #pragma unroll
        for (int r = 0; r < 4; ++r) {
            int row = rowBase + mtile * 16 + quad * 4 + r;
            if (row < nrows) H[(size_t)row * D + col] = f2b(acc[n][r]);
        }
    }
}

// ---------- aggregate by gather (bf16 rows): one wave per destination node ----------
__device__ inline void acc_row(const unsigned short* Hh, int c, float nw, int c4,
                               float& a0, float& a1, float& a2, float& a3) {
    uint2 p = *(const uint2*)&Hh[(size_t)c * D + c4];
    a0 = fmaf(b2f((unsigned short)(p.x & 0xffffu)), nw, a0);
    a1 = fmaf(b2f((unsigned short)(p.x >> 16)),     nw, a1);
    a2 = fmaf(b2f((unsigned short)(p.y & 0xffffu)), nw, a2);
    a3 = fmaf(b2f((unsigned short)(p.y >> 16)),     nw, a3);
}

__global__ __launch_bounds__(256) void k_agg(const unsigned short* __restrict__ Hh,
                                             const int* __restrict__ rowptr, const int* __restrict__ ebuf,
                                             const float* __restrict__ dinv, const float* __restrict__ b,
                                             unsigned short* __restrict__ Xo, int n, int relu) {
    int node = blockIdx.x * 4 + (threadIdx.x >> 6);
    if (node >= n) return;
    int lane = threadIdx.x & 63;
    int c4 = lane * 4;

    float dn = dinv[node];
    float self = dn * dn;

    uint2 hp = *(const uint2*)&Hh[(size_t)node * D + c4];
    float4 bb = *(const float4*)&b[c4];
    float a0 = fmaf(b2f((unsigned short)(hp.x & 0xffffu)), self, bb.x);
    float a1 = fmaf(b2f((unsigned short)(hp.x >> 16)),     self, bb.y);
    float a2 = fmaf(b2f((unsigned short)(hp.y & 0xffffu)), self, bb.z);
    float a3 = fmaf(b2f((unsigned short)(hp.y >> 16)),     self, bb.w);

    int beg = rowptr[node], end = rowptr[node + 1];
    int j = beg;
    for (; j + 3 < end; j += 4) {
        int cA = ebuf[j], cB = ebuf[j + 1], cC = ebuf[j + 2], cD = ebuf[j + 3];
        float nA = dn * dinv[cA], nB = dn * dinv[cB], nC = dn * dinv[cC], nD = dn * dinv[cD];
        acc_row(Hh, cA, nA, c4, a0, a1, a2, a3);
        acc_row(Hh, cB, nB, c4, a0, a1, a2, a3);
        acc_row(Hh, cC, nC, c4, a0, a1, a2, a3);
        acc_row(Hh, cD, nD, c4, a0, a1, a2, a3);
    }
    for (; j < end; ++j) {
        int cA = ebuf[j];
        acc_row(Hh, cA, dn * dinv[cA], c4, a0, a1, a2, a3);
    }
    if (relu) {
        a0 = fmaxf(a0, 0.f); a1 = fmaxf(a1, 0.f);
        a2 = fmaxf(a2, 0.f); a3 = fmaxf(a3, 0.f);
    }
    uint2 pk;
    pk.x = (unsigned int)f2b(a0) | ((unsigned int)f2b(a1) << 16);
    pk.y = (unsigned int)f2b(a2) | ((unsigned int)f2b(a3) << 16);
    *(uint2*)&Xo[(size_t)node * D + c4] = pk;
}

// ---------- link predictor: 32 q/block, async UV staging, A-frags built in registers ----------
// stage 0: async copy u-row|v-row (512B each) into padded UV region per q.
// stage 1: wave w owns ntiles w*4..w*4+3 (B read once/block) and both mtiles;
//          A-frag = ds_read_b128(u chunk) * ds_read_b128(v chunk) in registers. No Gs tile.
__global__ __launch_bounds__(256) void k_linkpred(const int* __restrict__ u, const int* __restrict__ v,
                                                  const unsigned short* __restrict__ X16,
                                                  const unsigned short* __restrict__ Bpack,
                                                  const float* __restrict__ P1b,
                                                  const float* __restrict__ P2w, const float* __restrict__ P2b,
                                                  float* __restrict__ out, int Q) {
    __shared__ unsigned short UV[32 * UVPITCH];   // 33,280 B
    __shared__ float red[4][32];

    int t = threadIdx.x;
    int w = t >> 6, lane = t & 63;
    int quad = lane >> 4, lcol = lane & 15;
    int q0 = blockIdx.x * 32;

    // ---- stage 0: async gather of endpoint rows (8 q per wave, 16B/lane) ----
    for (int i = 0; i < 8; ++i) {
        int q = w * 8 + i;
        int qq = q0 + q;
        int qc = (qq < Q) ? qq : 0;
        int ua = u[qc], va = v[qc];
        const char* src = (lane < 32)
            ? (const char*)(X16 + (size_t)ua * D) + lane * 16
            : (const char*)(X16 + (size_t)va * D) + (lane - 32) * 16;
        async_ld16(src, (char*)UV + q * (UVPITCH * 2) + lane * 16);
    }
    asm volatile("s_waitcnt vmcnt(0)" ::: "memory");
    __syncthreads();

    // ---- stage 1: MFMA with register-built A-frags ----
    frag_cd acc[2][4];
    #pragma unroll
    for (int m = 0; m < 2; ++m)
        #pragma unroll
        for (int jn = 0; jn < 4; ++jn) acc[m][jn] = (frag_cd){0.f, 0.f, 0.f, 0.f};

    const frag_ab* bp = (const frag_ab*)Bpack;
    for (int kt = 0; kt < 8; ++kt) {
        int ko = kt * 32 + quad * 8;
        union { frag_ab f; uint4 qv; } a[2];
        #pragma unroll
        for (int m = 0; m < 2; ++m) {
            const unsigned short* base = &UV[(m * 16 + lcol) * UVPITCH];
            uint4 au = *(const uint4*)(base + ko);
            uint4 av = *(const uint4*)(base + 256 + ko);
            a[m].qv.x = bmul2(au.x, av.x);
            a[m].qv.y = bmul2(au.y, av.y);
            a[m].qv.z = bmul2(au.z, av.z);
            a[m].qv.w = bmul2(au.w, av.w);
        }
        #pragma unroll
        for (int jn = 0; jn < 4; ++jn) {
            frag_ab b = bp[((w * 4 + jn) * 8 + kt) * 64 + lane];
            acc[0][jn] = __builtin_amdgcn_mfma_f32_16x16x32_bf16(a[0].f, b, acc[0][jn], 0, 0, 0);
            acc[1][jn] = __builtin_amdgcn_mfma_f32_16x16x32_bf16(a[1].f, b, acc[1][jn], 0, 0, 0);
        }
    }

    // ---- epilogue: relu(H+b1) . P2w, partial over this wave's 4 ntiles ----
    float part[2][4] = {{0.f,0.f,0.f,0.f},{0.f,0.f,0.f,0.f}};
    #pragma unroll
    for (int jn = 0; jn < 4; ++jn) {
        int col = (w * 4 + jn) * 16 + lcol;
        float bb = P1b[col];
        float pw = P2w[col];
        #pragma unroll
        for (int m = 0; m < 2; ++m)
            #pragma unroll
            for (int r = 0; r < 4; ++r)
                part[m][r] = fmaf(fmaxf(acc[m][jn][r] + bb, 0.f), pw, part[m][r]);
    }
    #pragma unroll
    for (int m = 0; m < 2; ++m)
        #pragma unroll
        for (int r = 0; r < 4; ++r) {
            float s = part[m][r];
            s += __shfl_down(s, 8);
            s += __shfl_down(s, 4);
            s += __shfl_down(s, 2);
            s += __shfl_down(s, 1);
            part[m][r] = s;
        }
    if (lcol == 0) {
        #pragma unroll
        for (int m = 0; m < 2; ++m)
            #pragma unroll
            for (int r = 0; r < 4; ++r)
                red[w][m * 16 + quad * 4 + r] = part[m][r];
    }
    __syncthreads();

    if (t < 32) {
        int qq = q0 + t;
        if (qq < Q) {
            float s = red[0][t] + red[1][t] + red[2][t] + red[3][t] + P2b[0];
            out[qq] = 1.0f / (1.0f + expf(-s));
        }
    }
}

extern "C" void kernel_launch(void* const* d_in, const int* in_sizes, int n_in,
                              void* d_out, int out_size, void* d_ws, size_t ws_size,
                              hipStream_t stream) {
    const int*   edge_index = (const int*)d_in[0];
    const int*   edges      = (const int*)d_in[1];
    const float* emb        = (const float*)d_in[2];
    const float* W1         = (const float*)d_in[3];
    const float* b1         = (const float*)d_in[4];
    const float* W2         = (const float*)d_in[5];
    const float* b2         = (const float*)d_in[6];
    const float* P1w        = (const float*)d_in[7];
    const float* P1b        = (const float*)d_in[8];
    const float* P2w        = (const float*)d_in[9];
    const float* P2b        = (const float*)d_in[10];

    int E  = in_sizes[0] / 2;
    int Q  = in_sizes[1] / 2;
    int Nn = in_sizes[2] / D;

    const int* rowp = edge_index;
    const int* colp = edge_index + E;
    const int* uq   = edges;
    const int* vq   = edges + Q;
    float* out = (float*)d_out;

    // ---- workspace layout ----
    char* ws = (char*)d_ws;
    size_t off = 0;
    auto alloc = [&](size_t bytes) -> char* {
        char* p = ws + off;
        off = (off + bytes + 255) & ~(size_t)255;
        return p;
    };
    float*          dinv   = (float*)alloc((size_t)Nn * 4);
    int*            rowptr = (int*)  alloc(((size_t)Nn + 1) * 4);
    int*            ebuf   = (int*)  alloc((size_t)E * 4);
    unsigned short* BpW1   = (unsigned short*)alloc(65536 * 2);
    unsigned short* BpW2   = (unsigned short*)alloc(65536 * 2);
    unsigned short* BpP1   = (unsigned short*)alloc(65536 * 2);
    unsigned short* hbuf   = (unsigned short*)alloc((size_t)Nn * D * 2);  // bf16
    unsigned short* xbuf   = (unsigned short*)alloc((size_t)Nn * D * 2);  // bf16

    // CSR temporaries aliased into xbuf (dead until first k_agg writes it)
    int* degi  = (int*)xbuf;
    int* fill  = degi + Nn;
    int* bsums = degi + 2 * Nn;

    int nb;
    int nscan = (Nn + SCAN_CHUNK - 1) / SCAN_CHUNK;

    // CSR build
    nb = (2 * Nn + 255) / 256; k_zero_int<<<nb, 256, 0, stream>>>(degi, 2 * Nn);
    nb = (E + 255) / 256;      k_count_int<<<nb, 256, 0, stream>>>(rowp, degi, E);
    k_scan_block<<<nscan, 256, 0, stream>>>(degi, rowptr, bsums, Nn);
    k_scan_bsums<<<1, 256, 0, stream>>>(bsums, nscan);
    nb = (Nn + 255) / 256;     k_scan_add<<<nb, 256, 0, stream>>>(rowptr, bsums, Nn, E);
    nb = (Nn + 255) / 256;     k_dinv<<<nb, 256, 0, stream>>>(degi, dinv, Nn);
    nb = (E + 255) / 256;      k_bucket<<<nb, 256, 0, stream>>>(rowp, colp, rowptr, fill, ebuf, E);

    // pack weights for MFMA B operand
    k_packB<<<256, 256, 0, stream>>>(W1, BpW1);
    k_packB<<<256, 256, 0, stream>>>(W2, BpW2);
    k_packB<<<256, 256, 0, stream>>>(P1w, BpP1);

    // conv1: h = emb @ W1 (MFMA, fp32 A) ; x1 = relu(norm-agg(h) + b1)  [bf16]
    nb = (Nn + 31) / 32; k_gemm_mfma<<<nb, 256, 0, stream>>>((const void*)emb, 1, BpW1, hbuf, Nn);
    nb = (Nn + 3) / 4;   k_agg<<<nb, 256, 0, stream>>>(hbuf, rowptr, ebuf, dinv, b1, xbuf, Nn, 1);

    // conv2: h = x1 @ W2 (MFMA, bf16 A) ; x2 = norm-agg(h) + b2          [bf16]
    nb = (Nn + 31) / 32; k_gemm_mfma<<<nb, 256, 0, stream>>>((const void*)xbuf, 0, BpW2, hbuf, Nn);
    nb = (Nn + 3) / 4;   k_agg<<<nb, 256, 0, stream>>>(hbuf, rowptr, ebuf, dinv, b2, xbuf, Nn, 0);

    // link predictor (async UV staging, register A-frags, MFMA bf16)
    nb = (Q + 31) / 32;  k_linkpred<<<nb, 256, 0, stream>>>(uq, vq, xbuf, BpP1, P1b, P2w, P2b, out, Q);
}

// Round 9
// 458.753 us; speedup vs baseline: 1.1145x; 1.0155x over previous
//
#include <hip/hip_runtime.h>
#include <math.h>

#define D 256
#define SCAN_CHUNK 1024
#define GPITCH 264    // bf16 LDS pitch for MFMA A tiles (pad 8) — verified pattern r3-r8
#define UVPITCH 520   // bf16 pitch per query region: 256 u | 256 v | 8 pad (1040 B, 16B-aligned)

typedef __attribute__((ext_vector_type(8))) short frag_ab;   // 8 bf16
typedef __attribute__((ext_vector_type(4))) float frag_cd;   // 4 fp32

__device__ inline unsigned short f2b(float f) {
    unsigned int u = __float_as_uint(f);
    u += 0x7fffu + ((u >> 16) & 1u);
    return (unsigned short)(u >> 16);
}
__device__ inline float b2f(unsigned short h) {
    return __uint_as_float(((unsigned int)h) << 16);
}
// elementwise product of two packed bf16 pairs -> packed bf16 pair (TRUNCATING, 7 VALU ops)
__device__ inline unsigned int bmul2t(unsigned int a, unsigned int b) {
    float a0 = __uint_as_float(a << 16);
    float a1 = __uint_as_float(a & 0xffff0000u);
    float b0 = __uint_as_float(b << 16);
    float b1 = __uint_as_float(b & 0xffff0000u);
    float p0 = a0 * b0, p1 = a1 * b1;
    // out = (hi16(p1) << 16) | hi16(p0)
    return __builtin_amdgcn_perm(__float_as_uint(p1), __float_as_uint(p0), 0x07060302);
}

// async global->LDS, 16B per lane; LDS dest = wave-uniform base + lane*16
__device__ inline void async_ld16(const void* g, void* l) {
    __builtin_amdgcn_global_load_lds(
        (const __attribute__((address_space(1))) void*)g,
        (__attribute__((address_space(3))) void*)l,
        16, 0, 0);
}

// ---------- zero int buffer ----------
__global__ void k_zero_int(int* p, int n) {
    int i = blockIdx.x * 256 + threadIdx.x;
    if (i < n) p[i] = 0;
}

// ---------- int degree count ----------
__global__ void k_count_int(const int* __restrict__ row, int* deg, int E) {
    int e = blockIdx.x * 256 + threadIdx.x;
    if (e < E) atomicAdd(&deg[row[e]], 1);
}

// ---------- prefix scan (3 stages); excl written into rowptr ----------
__global__ __launch_bounds__(256) void k_scan_block(const int* __restrict__ deg, int* __restrict__ excl,
                                                    int* __restrict__ bsums, int n) {
    __shared__ int s[256];
    int blk = blockIdx.x, t = threadIdx.x;
    int base = blk * SCAN_CHUNK + t * 4;
    int v0 = (base + 0 < n) ? deg[base + 0] : 0;
    int v1 = (base + 1 < n) ? deg[base + 1] : 0;
    int v2 = (base + 2 < n) ? deg[base + 2] : 0;
    int v3 = (base + 3 < n) ? deg[base + 3] : 0;
    int tsum = v0 + v1 + v2 + v3;
    s[t] = tsum;
    __syncthreads();
    for (int off = 1; off < 256; off <<= 1) {
        int x = (t >= off) ? s[t - off] : 0;
        __syncthreads();
        s[t] += x;
        __syncthreads();
    }
    int run = s[t] - tsum;
    if (t == 255) bsums[blk] = s[255];
    if (base + 0 < n) excl[base + 0] = run;
    run += v0;
    if (base + 1 < n) excl[base + 1] = run;
    run += v1;
    if (base + 2 < n) excl[base + 2] = run;
    run += v2;
    if (base + 3 < n) excl[base + 3] = run;
}

__global__ __launch_bounds__(256) void k_scan_bsums(int* bsums, int nb) {
    __shared__ int s[256];
    int t = threadIdx.x;
    int v = (t < nb) ? bsums[t] : 0;
    s[t] = v;
    __syncthreads();
    for (int off = 1; off < 256; off <<= 1) {
        int x = (t >= off) ? s[t - off] : 0;
        __syncthreads();
        s[t] += x;
        __syncthreads();
    }
    if (t < nb) bsums[t] = s[t] - v;
}

// fused: rowptr[i] += bsums[i/SCAN_CHUNK]  AND  dinv[i] = rsqrt(deg[i]+1)
__global__ void k_scan_add_dinv(int* __restrict__ rowptr, const int* __restrict__ bsums,
                                const int* __restrict__ deg, float* __restrict__ dinv,
                                int n, int total) {
    int i = blockIdx.x * 256 + threadIdx.x;
    if (i < n) {
        rowptr[i] += bsums[i / SCAN_CHUNK];
        dinv[i] = rsqrtf((float)(deg[i] + 1));
    }
    if (i == 0) rowptr[n] = total;
}

// ---------- bucket edges into CSR ----------
__global__ void k_bucket(const int* __restrict__ row, const int* __restrict__ col,
                         const int* __restrict__ rowptr, int* __restrict__ fill,
                         int* __restrict__ ebuf, int E) {
    int e = blockIdx.x * 256 + threadIdx.x;
    if (e >= E) return;
    int r = row[e];
    int pos = atomicAdd(&fill[r], 1);
    ebuf[rowptr[r] + pos] = col[e];
}

// ---------- pack three fp32 [k][n] weights into MFMA B-fragment order (bf16) ----------
__global__ void k_packB3(const float* __restrict__ Wa, const float* __restrict__ Wb,
                         const float* __restrict__ Wc,
                         unsigned short* __restrict__ Ba, unsigned short* __restrict__ Bb,
                         unsigned short* __restrict__ Bc) {
    int which = blockIdx.x >> 8;
    int i = (blockIdx.x & 255) * 256 + threadIdx.x;   // 65536 per weight
    const float* W = (which == 0) ? Wa : (which == 1) ? Wb : Wc;
    unsigned short* Bp = (which == 0) ? Ba : (which == 1) ? Bb : Bc;
    int ntile = i >> 12;
    int kt = (i >> 9) & 7;
    int lane = (i >> 3) & 63;
    int j = i & 7;
    int k = kt * 32 + (lane >> 4) * 8 + j;
    int n = ntile * 16 + (lane & 15);
    Bp[i] = f2b(W[k * D + n]);
}

// ---------- MFMA GEMM: H16[nrows,256] = X[nrows,256] @ W  (bf16 in/out, fp32 acc) ----------
__global__ __launch_bounds__(256) void k_gemm_mfma(const void* __restrict__ X, int xIsF32,
                                                   const unsigned short* __restrict__ Bpack,
                                                   unsigned short* __restrict__ H, int nrows) {
    __shared__ unsigned short As[32 * GPITCH];
    int t = threadIdx.x;
    int rowBase = blockIdx.x * 32;

    {
        int half = t >> 7;
        int cpair = t & 127;
        for (int qi = 0; qi < 32; qi += 2) {
            int q = qi + half;
            int r = rowBase + q;
            unsigned int val = 0;
            if (r < nrows) {
                if (xIsF32) {
                    const float* xr = (const float*)X + (size_t)r * D + cpair * 2;
                    val = (unsigned int)f2b(xr[0]) | ((unsigned int)f2b(xr[1]) << 16);
                } else {
                    val = ((const unsigned int*)((const unsigned short*)X + (size_t)r * D))[cpair];
                }
            }
            *(unsigned int*)&As[q * GPITCH + cpair * 2] = val;
        }
    }
    __syncthreads();

    int w = t >> 6, lane = t & 63;
    int mtile = w >> 1;
    int nhalf = w & 1;
    int quad = lane >> 4, lcol = lane & 15;

    frag_cd acc[8];
    #pragma unroll
    for (int n = 0; n < 8; ++n) acc[n] = (frag_cd){0.f, 0.f, 0.f, 0.f};

    const frag_ab* bp = (const frag_ab*)Bpack;
    for (int kt = 0; kt < 8; ++kt) {
        frag_ab a = *(const frag_ab*)&As[(mtile * 16 + lcol) * GPITCH + kt * 32 + quad * 8];
        #pragma unroll
        for (int n = 0; n < 8; ++n) {
            frag_ab b = bp[((nhalf * 8 + n) * 8 + kt) * 64 + lane];
            acc[n] = __builtin_amdgcn_mfma_f32_16x16x32_bf16(a, b, acc[n], 0, 0, 0);
        }
    }

    #pragma unroll
    for (int n = 0; n < 8; ++n) {
        int col = (nhalf * 8 + n) * 16 + lcol;
        #pragma unroll
        for (int r = 0; r < 4; ++r) {
            int row = rowBase + mtile * 16 + quad * 4 + r;
            if (row < nrows) H[(size_t)row * D + col] = f2b(acc[n][r]);
        }
    }
}

// ---------- aggregate by gather (bf16 rows): one wave per destination node ----------
__device__ inline void acc_row(const unsigned short* Hh, int c, float nw, int c4,
                               float& a0, float& a1, float& a2, float& a3) {
    uint2 p = *(const uint2*)&Hh[(size_t)c * D + c4];
    a0 = fmaf(b2f((unsigned short)(p.x & 0xffffu)), nw, a0);
    a1 = fmaf(b2f((unsigned short)(p.x >> 16)),     nw, a1);
    a2 = fmaf(b2f((unsigned short)(p.y & 0xffffu)), nw, a2);
    a3 = fmaf(b2f((unsigned short)(p.y >> 16)),     nw, a3);
}

__global__ __launch_bounds__(256) void k_agg(const unsigned short* __restrict__ Hh,
                                             const int* __restrict__ rowptr, const int* __restrict__ ebuf,
                                             const float* __restrict__ dinv, const float* __restrict__ b,
                                             unsigned short* __restrict__ Xo, int n, int relu) {
    int node = blockIdx.x * 4 + (threadIdx.x >> 6);
    if (node >= n) return;
    int lane = threadIdx.x & 63;
    int c4 = lane * 4;

    float dn = dinv[node];
    float self = dn * dn;

    uint2 hp = *(const uint2*)&Hh[(size_t)node * D + c4];
    float4 bb = *(const float4*)&b[c4];
    float a0 = fmaf(b2f((unsigned short)(hp.x & 0xffffu)), self, bb.x);
    float a1 = fmaf(b2f((unsigned short)(hp.x >> 16)),     self, bb.y);
    float a2 = fmaf(b2f((unsigned short)(hp.y & 0xffffu)), self, bb.z);
    float a3 = fmaf(b2f((unsigned short)(hp.y >> 16)),     self, bb.w);

    int beg = rowptr[node], end = rowptr[node + 1];
    int j = beg;
    for (; j + 3 < end; j += 4) {
        int cA = ebuf[j], cB = ebuf[j + 1], cC = ebuf[j + 2], cD = ebuf[j + 3];
        float nA = dn * dinv[cA], nB = dn * dinv[cB], nC = dn * dinv[cC], nD = dn * dinv[cD];
        acc_row(Hh, cA, nA, c4, a0, a1, a2, a3);
        acc_row(Hh, cB, nB, c4, a0, a1, a2, a3);
        acc_row(Hh, cC, nC, c4, a0, a1, a2, a3);
        acc_row(Hh, cD, nD, c4, a0, a1, a2, a3);
    }
    for (; j < end; ++j) {
        int cA = ebuf[j];
        acc_row(Hh, cA, dn * dinv[cA], c4, a0, a1, a2, a3);
    }
    if (relu) {
        a0 = fmaxf(a0, 0.f); a1 = fmaxf(a1, 0.f);
        a2 = fmaxf(a2, 0.f); a3 = fmaxf(a3, 0.f);
    }
    uint2 pk;
    pk.x = (unsigned int)f2b(a0) | ((unsigned int)f2b(a1) << 16);
    pk.y = (unsigned int)f2b(a2) | ((unsigned int)f2b(a3) << 16);
    *(uint2*)&Xo[(size_t)node * D + c4] = pk;
}

// ---------- link predictor: 32 q/block ----------
// stage 0: wave w async-stages its 8 queries' u|v rows into padded UV.
// stage 1: wave w computes the bf16 products for ITS OWN 8 rows once (bmul2t) -> Gs.
//          (no barrier needed before stage 1: vmcnt(0) covers the wave's own loads)
// stage 2: MFMA from Gs (r4-verified A-frag pattern); wave w owns ntiles w*4..w*4+3
//          (B read once per block) and both mtiles.
__global__ __launch_bounds__(256) void k_linkpred(const int* __restrict__ u, const int* __restrict__ v,
                                                  const unsigned short* __restrict__ X16,
                                                  const unsigned short* __restrict__ Bpack,
                                                  const float* __restrict__ P1b,
                                                  const float* __restrict__ P2w, const float* __restrict__ P2b,
                                                  float* __restrict__ out, int Q) {
    __shared__ unsigned short UV[32 * UVPITCH];   // 33,280 B
    __shared__ unsigned short Gs[32 * GPITCH];    // 16,896 B
    __shared__ float red[4][32];

    int t = threadIdx.x;
    int w = t >> 6, lane = t & 63;
    int quad = lane >> 4, lcol = lane & 15;
    int q0 = blockIdx.x * 32;

    // ---- stage 0: async gather of endpoint rows (8 q per wave, 16B/lane) ----
    for (int i = 0; i < 8; ++i) {
        int q = w * 8 + i;
        int qq = q0 + q;
        int qc = (qq < Q) ? qq : 0;
        int ua = u[qc], va = v[qc];
        const char* src = (lane < 32)
            ? (const char*)(X16 + (size_t)ua * D) + lane * 16
            : (const char*)(X16 + (size_t)va * D) + (lane - 32) * 16;
        async_ld16(src, (char*)UV + q * (UVPITCH * 2) + lane * 16);
    }
    asm volatile("s_waitcnt vmcnt(0)" ::: "memory");

    // ---- stage 1: products for this wave's own 8 rows (computed ONCE per block) ----
    {
        int q = w * 8 + (lane >> 3);     // own wave's staged rows
        int c = lane & 7;                // 32-col chunk
        const uint4* pu = (const uint4*)&UV[q * UVPITCH + c * 32];
        const uint4* pv = (const uint4*)&UV[q * UVPITCH + 256 + c * 32];
        uint4* pg = (uint4*)&Gs[q * GPITCH + c * 32];
        #pragma unroll
        for (int j = 0; j < 4; ++j) {
            uint4 a = pu[j], b = pv[j];
            uint4 r;
            r.x = bmul2t(a.x, b.x);
            r.y = bmul2t(a.y, b.y);
            r.z = bmul2t(a.z, b.z);
            r.w = bmul2t(a.w, b.w);
            pg[j] = r;
        }
    }
    __syncthreads();

    // ---- stage 2: MFMA — wave w owns ntiles w*4..w*4+3, both mtiles ----
    frag_cd acc[2][4];
    #pragma unroll
    for (int m = 0; m < 2; ++m)
        #pragma unroll
        for (int jn = 0; jn < 4; ++jn) acc[m][jn] = (frag_cd){0.f, 0.f, 0.f, 0.f};

    const frag_ab* bp = (const frag_ab*)Bpack;
    for (int kt = 0; kt < 8; ++kt) {
        frag_ab a0 = *(const frag_ab*)&Gs[lcol * GPITCH + kt * 32 + quad * 8];
        frag_ab a1 = *(const frag_ab*)&Gs[(16 + lcol) * GPITCH + kt * 32 + quad * 8];
        #pragma unroll
        for (int jn = 0; jn < 4; ++jn) {
            frag_ab b = bp[((w * 4 + jn) * 8 + kt) * 64 + lane];
            acc[0][jn] = __builtin_amdgcn_mfma_f32_16x16x32_bf16(a0, b, acc[0][jn], 0, 0, 0);
            acc[1][jn] = __builtin_amdgcn_mfma_f32_16x16x32_bf16(a1, b, acc[1][jn], 0, 0, 0);
        }
    }

    // ---- epilogue: relu(H+b1) . P2w, partial over this wave's 4 ntiles ----
    float part[2][4] = {{0.f,0.f,0.f,0.f},{0.f,0.f,0.f,0.f}};
    #pragma unroll
    for (int jn = 0; jn < 4; ++jn) {
        int col = (w * 4 + jn) * 16 + lcol;
        float bb = P1b[col];
        float pw = P2w[col];
        #pragma unroll
        for (int m = 0; m < 2; ++m)
            #pragma unroll
            for (int r = 0; r < 4; ++r)
                part[m][r] = fmaf(fmaxf(acc[m][jn][r] + bb, 0.f), pw, part[m][r]);
    }
    #pragma unroll
    for (int m = 0; m < 2; ++m)
        #pragma unroll
        for (int r = 0; r < 4; ++r) {
            float s = part[m][r];
            s += __shfl_down(s, 8);
            s += __shfl_down(s, 4);
            s += __shfl_down(s, 2);
            s += __shfl_down(s, 1);
            part[m][r] = s;
        }
    if (lcol == 0) {
        #pragma unroll
        for (int m = 0; m < 2; ++m)
            #pragma unroll
            for (int r = 0; r < 4; ++r)
                red[w][m * 16 + quad * 4 + r] = part[m][r];
    }
    __syncthreads();

    if (t < 32) {
        int qq = q0 + t;
        if (qq < Q) {
            float s = red[0][t] + red[1][t] + red[2][t] + red[3][t] + P2b[0];
            out[qq] = 1.0f / (1.0f + expf(-s));
        }
    }
}

extern "C" void kernel_launch(void* const* d_in, const int* in_sizes, int n_in,
                              void* d_out, int out_size, void* d_ws, size_t ws_size,
                              hipStream_t stream) {
    const int*   edge_index = (const int*)d_in[0];
    const int*   edges      = (const int*)d_in[1];
    const float* emb        = (const float*)d_in[2];
    const float* W1         = (const float*)d_in[3];
    const float* b1         = (const float*)d_in[4];
    const float* W2         = (const float*)d_in[5];
    const float* b2         = (const float*)d_in[6];
    const float* P1w        = (const float*)d_in[7];
    const float* P1b        = (const float*)d_in[8];
    const float* P2w        = (const float*)d_in[9];
    const float* P2b        = (const float*)d_in[10];

    int E  = in_sizes[0] / 2;
    int Q  = in_sizes[1] / 2;
    int Nn = in_sizes[2] / D;

    const int* rowp = edge_index;
    const int* colp = edge_index + E;
    const int* uq   = edges;
    const int* vq   = edges + Q;
    float* out = (float*)d_out;

    // ---- workspace layout ----
    char* ws = (char*)d_ws;
    size_t off = 0;
    auto alloc = [&](size_t bytes) -> char* {
        char* p = ws + off;
        off = (off + bytes + 255) & ~(size_t)255;
        return p;
    };
    float*          dinv   = (float*)alloc((size_t)Nn * 4);
    int*            rowptr = (int*)  alloc(((size_t)Nn + 1) * 4);
    int*            ebuf   = (int*)  alloc((size_t)E * 4);
    unsigned short* BpW1   = (unsigned short*)alloc(65536 * 2);
    unsigned short* BpW2   = (unsigned short*)alloc(65536 * 2);
    unsigned short* BpP1   = (unsigned short*)alloc(65536 * 2);
    unsigned short* hbuf   = (unsigned short*)alloc((size_t)Nn * D * 2);  // bf16
    unsigned short* xbuf   = (unsigned short*)alloc((size_t)Nn * D * 2);  // bf16

    // CSR temporaries aliased into xbuf (dead until first k_agg writes it)
    int* degi  = (int*)xbuf;
    int* fill  = degi + Nn;
    int* bsums = degi + 2 * Nn;

    int nb;
    int nscan = (Nn + SCAN_CHUNK - 1) / SCAN_CHUNK;

    // CSR build
    nb = (2 * Nn + 255) / 256; k_zero_int<<<nb, 256, 0, stream>>>(degi, 2 * Nn);
    nb = (E + 255) / 256;      k_count_int<<<nb, 256, 0, stream>>>(rowp, degi, E);
    k_scan_block<<<nscan, 256, 0, stream>>>(degi, rowptr, bsums, Nn);
    k_scan_bsums<<<1, 256, 0, stream>>>(bsums, nscan);
    nb = (Nn + 255) / 256;     k_scan_add_dinv<<<nb, 256, 0, stream>>>(rowptr, bsums, degi, dinv, Nn, E);
    nb = (E + 255) / 256;      k_bucket<<<nb, 256, 0, stream>>>(rowp, colp, rowptr, fill, ebuf, E);

    // pack all three weights for MFMA B operand (one launch)
    k_packB3<<<768, 256, 0, stream>>>(W1, W2, P1w, BpW1, BpW2, BpP1);

    // conv1: h = emb @ W1 (MFMA, fp32 A) ; x1 = relu(norm-agg(h) + b1)  [bf16]
    nb = (Nn + 31) / 32; k_gemm_mfma<<<nb, 256, 0, stream>>>((const void*)emb, 1, BpW1, hbuf, Nn);
    nb = (Nn + 3) / 4;   k_agg<<<nb, 256, 0, stream>>>(hbuf, rowptr, ebuf, dinv, b1, xbuf, Nn, 1);

    // conv2: h = x1 @ W2 (MFMA, bf16 A) ; x2 = norm-agg(h) + b2          [bf16]
    nb = (Nn + 31) / 32; k_gemm_mfma<<<nb, 256, 0, stream>>>((const void*)xbuf, 0, BpW2, hbuf, Nn);
    nb = (Nn + 3) / 4;   k_agg<<<nb, 256, 0, stream>>>(hbuf, rowptr, ebuf, dinv, b2, xbuf, Nn, 0);

    // link predictor (async UV staging, deduped products -> Gs, MFMA bf16)
    nb = (Q + 31) / 32;  k_linkpred<<<nb, 256, 0, stream>>>(uq, vq, xbuf, BpP1, P1b, P2w, P2b, out, Q);
}

// Round 10
// 438.536 us; speedup vs baseline: 1.1658x; 1.0461x over previous
//
#include <hip/hip_runtime.h>
#include <math.h>

#define D 256
#define SCAN_CHUNK 1024
#define GPITCH 264    // bf16 LDS pitch for MFMA A tiles (pad 8) — verified pattern r3-r9
#define UVPITCH 520   // bf16 pitch per query region: 256 u | 256 v | 8 pad (1040 B, 16B-aligned)

typedef __attribute__((ext_vector_type(8))) short frag_ab;   // 8 bf16
typedef __attribute__((ext_vector_type(4))) float frag_cd;   // 4 fp32

__device__ inline unsigned short f2b(float f) {
    unsigned int u = __float_as_uint(f);
    u += 0x7fffu + ((u >> 16) & 1u);
    return (unsigned short)(u >> 16);
}
__device__ inline float b2f(unsigned short h) {
    return __uint_as_float(((unsigned int)h) << 16);
}
// elementwise product of two packed bf16 pairs -> packed bf16 pair (TRUNCATING, 7 VALU ops)
__device__ inline unsigned int bmul2t(unsigned int a, unsigned int b) {
    float a0 = __uint_as_float(a << 16);
    float a1 = __uint_as_float(a & 0xffff0000u);
    float b0 = __uint_as_float(b << 16);
    float b1 = __uint_as_float(b & 0xffff0000u);
    float p0 = a0 * b0, p1 = a1 * b1;
    // out = (hi16(p1) << 16) | hi16(p0)
    return __builtin_amdgcn_perm(__float_as_uint(p1), __float_as_uint(p0), 0x07060302);
}

// async global->LDS, 16B per lane; LDS dest = wave-uniform base + lane*16
__device__ inline void async_ld16(const void* g, void* l) {
    __builtin_amdgcn_global_load_lds(
        (const __attribute__((address_space(1))) void*)g,
        (__attribute__((address_space(3))) void*)l,
        16, 0, 0);
}

// ---------- zero int buffer ----------
__global__ void k_zero_int(int* p, int n) {
    int i = blockIdx.x * 256 + threadIdx.x;
    if (i < n) p[i] = 0;
}

// ---------- int degree count ----------
__global__ void k_count_int(const int* __restrict__ row, int* deg, int E) {
    int e = blockIdx.x * 256 + threadIdx.x;
    if (e < E) atomicAdd(&deg[row[e]], 1);
}

// ---------- prefix scan (3 stages); excl written into rowptr ----------
__global__ __launch_bounds__(256) void k_scan_block(const int* __restrict__ deg, int* __restrict__ excl,
                                                    int* __restrict__ bsums, int n) {
    __shared__ int s[256];
    int blk = blockIdx.x, t = threadIdx.x;
    int base = blk * SCAN_CHUNK + t * 4;
    int v0 = (base + 0 < n) ? deg[base + 0] : 0;
    int v1 = (base + 1 < n) ? deg[base + 1] : 0;
    int v2 = (base + 2 < n) ? deg[base + 2] : 0;
    int v3 = (base + 3 < n) ? deg[base + 3] : 0;
    int tsum = v0 + v1 + v2 + v3;
    s[t] = tsum;
    __syncthreads();
    for (int off = 1; off < 256; off <<= 1) {
        int x = (t >= off) ? s[t - off] : 0;
        __syncthreads();
        s[t] += x;
        __syncthreads();
    }
    int run = s[t] - tsum;
    if (t == 255) bsums[blk] = s[255];
    if (base + 0 < n) excl[base + 0] = run;
    run += v0;
    if (base + 1 < n) excl[base + 1] = run;
    run += v1;
    if (base + 2 < n) excl[base + 2] = run;
    run += v2;
    if (base + 3 < n) excl[base + 3] = run;
}

__global__ __launch_bounds__(256) void k_scan_bsums(int* bsums, int nb) {
    __shared__ int s[256];
    int t = threadIdx.x;
    int v = (t < nb) ? bsums[t] : 0;
    s[t] = v;
    __syncthreads();
    for (int off = 1; off < 256; off <<= 1) {
        int x = (t >= off) ? s[t - off] : 0;
        __syncthreads();
        s[t] += x;
        __syncthreads();
    }
    if (t < nb) bsums[t] = s[t] - v;
}

// fused: rowptr[i] += bsums[i/SCAN_CHUNK]  AND  dinv[i] = rsqrt(deg[i]+1)
__global__ void k_scan_add_dinv(int* __restrict__ rowptr, const int* __restrict__ bsums,
                                const int* __restrict__ deg, float* __restrict__ dinv,
                                int n, int total) {
    int i = blockIdx.x * 256 + threadIdx.x;
    if (i < n) {
        rowptr[i] += bsums[i / SCAN_CHUNK];
        dinv[i] = rsqrtf((float)(deg[i] + 1));
    }
    if (i == 0) rowptr[n] = total;
}

// ---------- bucket edges into CSR ----------
__global__ void k_bucket(const int* __restrict__ row, const int* __restrict__ col,
                         const int* __restrict__ rowptr, int* __restrict__ fill,
                         int* __restrict__ ebuf, int E) {
    int e = blockIdx.x * 256 + threadIdx.x;
    if (e >= E) return;
    int r = row[e];
    int pos = atomicAdd(&fill[r], 1);
    ebuf[rowptr[r] + pos] = col[e];
}

// ---------- pack three fp32 [k][n] weights into MFMA B-fragment order (bf16) ----------
__global__ void k_packB3(const float* __restrict__ Wa, const float* __restrict__ Wb,
                         const float* __restrict__ Wc,
                         unsigned short* __restrict__ Ba, unsigned short* __restrict__ Bb,
                         unsigned short* __restrict__ Bc) {
    int which = blockIdx.x >> 8;
    int i = (blockIdx.x & 255) * 256 + threadIdx.x;   // 65536 per weight
    const float* W = (which == 0) ? Wa : (which == 1) ? Wb : Wc;
    unsigned short* Bp = (which == 0) ? Ba : (which == 1) ? Bb : Bc;
    int ntile = i >> 12;
    int kt = (i >> 9) & 7;
    int lane = (i >> 3) & 63;
    int j = i & 7;
    int k = kt * 32 + (lane >> 4) * 8 + j;
    int n = ntile * 16 + (lane & 15);
    Bp[i] = f2b(W[k * D + n]);
}

// ---------- MFMA GEMM: H16[nrows,256] = X[nrows,256] @ W  (bf16 in/out, fp32 acc) ----------
__global__ __launch_bounds__(256) void k_gemm_mfma(const void* __restrict__ X, int xIsF32,
                                                   const unsigned short* __restrict__ Bpack,
                                                   unsigned short* __restrict__ H, int nrows) {
    __shared__ unsigned short As[32 * GPITCH];
    int t = threadIdx.x;
    int rowBase = blockIdx.x * 32;

    {
        int half = t >> 7;
        int cpair = t & 127;
        for (int qi = 0; qi < 32; qi += 2) {
            int q = qi + half;
            int r = rowBase + q;
            unsigned int val = 0;
            if (r < nrows) {
                if (xIsF32) {
                    const float* xr = (const float*)X + (size_t)r * D + cpair * 2;
                    val = (unsigned int)f2b(xr[0]) | ((unsigned int)f2b(xr[1]) << 16);
                } else {
                    val = ((const unsigned int*)((const unsigned short*)X + (size_t)r * D))[cpair];
                }
            }
            *(unsigned int*)&As[q * GPITCH + cpair * 2] = val;
        }
    }
    __syncthreads();

    int w = t >> 6, lane = t & 63;
    int mtile = w >> 1;
    int nhalf = w & 1;
    int quad = lane >> 4, lcol = lane & 15;

    frag_cd acc[8];
    #pragma unroll
    for (int n = 0; n < 8; ++n) acc[n] = (frag_cd){0.f, 0.f, 0.f, 0.f};

    const frag_ab* bp = (const frag_ab*)Bpack;
    for (int kt = 0; kt < 8; ++kt) {
        frag_ab a = *(const frag_ab*)&As[(mtile * 16 + lcol) * GPITCH + kt * 32 + quad * 8];
        #pragma unroll
        for (int n = 0; n < 8; ++n) {
            frag_ab b = bp[((nhalf * 8 + n) * 8 + kt) * 64 + lane];
            acc[n] = __builtin_amdgcn_mfma_f32_16x16x32_bf16(a, b, acc[n], 0, 0, 0);
        }
    }

    #pragma unroll
    for (int n = 0; n < 8; ++n) {
        int col = (nhalf * 8 + n) * 16 + lcol;
        #pragma unroll
        for (int r = 0; r < 4; ++r) {
            int row = rowBase + mtile * 16 + quad * 4 + r;
            if (row < nrows) H[(size_t)row * D + col] = f2b(acc[n][r]);
        }
    }
}

// ---------- aggregate by gather: 2 nodes per wave, 32 lanes (16B) per node ----------
__device__ inline void fma8(uint4 p, float nw, float* a) {
    a[0] = fmaf(b2f((unsigned short)(p.x & 0xffffu)), nw, a[0]);
    a[1] = fmaf(b2f((unsigned short)(p.x >> 16)),     nw, a[1]);
    a[2] = fmaf(b2f((unsigned short)(p.y & 0xffffu)), nw, a[2]);
    a[3] = fmaf(b2f((unsigned short)(p.y >> 16)),     nw, a[3]);
    a[4] = fmaf(b2f((unsigned short)(p.z & 0xffffu)), nw, a[4]);
    a[5] = fmaf(b2f((unsigned short)(p.z >> 16)),     nw, a[5]);
    a[6] = fmaf(b2f((unsigned short)(p.w & 0xffffu)), nw, a[6]);
    a[7] = fmaf(b2f((unsigned short)(p.w >> 16)),     nw, a[7]);
}

__global__ __launch_bounds__(256) void k_agg(const unsigned short* __restrict__ Hh,
                                             const int* __restrict__ rowptr, const int* __restrict__ ebuf,
                                             const float* __restrict__ dinv, const float* __restrict__ b,
                                             unsigned short* __restrict__ Xo, int n, int relu) {
    int w = threadIdx.x >> 6, lane = threadIdx.x & 63;
    int half = lane >> 5, sub = lane & 31;
    int node = (blockIdx.x * 4 + w) * 2 + half;
    if (node >= n) return;
    int c8 = sub * 8;

    float dn = dinv[node];
    float self = dn * dn;

    float acc[8];
    {
        uint4 hp = *(const uint4*)&Hh[(size_t)node * D + c8];
        float4 b0 = *(const float4*)&b[c8];
        float4 b1 = *(const float4*)&b[c8 + 4];
        acc[0] = b0.x; acc[1] = b0.y; acc[2] = b0.z; acc[3] = b0.w;
        acc[4] = b1.x; acc[5] = b1.y; acc[6] = b1.z; acc[7] = b1.w;
        fma8(hp, self, acc);
    }

    int beg = rowptr[node], end = rowptr[node + 1];
    int j = beg;
    for (; j + 3 < end; j += 4) {
        int cA = ebuf[j], cB = ebuf[j + 1], cC = ebuf[j + 2], cD = ebuf[j + 3];
        float nA = dn * dinv[cA], nB = dn * dinv[cB], nC = dn * dinv[cC], nD = dn * dinv[cD];
        uint4 pA = *(const uint4*)&Hh[(size_t)cA * D + c8];
        uint4 pB = *(const uint4*)&Hh[(size_t)cB * D + c8];
        uint4 pC = *(const uint4*)&Hh[(size_t)cC * D + c8];
        uint4 pD = *(const uint4*)&Hh[(size_t)cD * D + c8];
        fma8(pA, nA, acc);
        fma8(pB, nB, acc);
        fma8(pC, nC, acc);
        fma8(pD, nD, acc);
    }
    for (; j < end; ++j) {
        int cA = ebuf[j];
        uint4 pA = *(const uint4*)&Hh[(size_t)cA * D + c8];
        fma8(pA, dn * dinv[cA], acc);
    }
    if (relu) {
        #pragma unroll
        for (int i = 0; i < 8; ++i) acc[i] = fmaxf(acc[i], 0.f);
    }
    uint4 pk;
    pk.x = (unsigned int)f2b(acc[0]) | ((unsigned int)f2b(acc[1]) << 16);
    pk.y = (unsigned int)f2b(acc[2]) | ((unsigned int)f2b(acc[3]) << 16);
    pk.z = (unsigned int)f2b(acc[4]) | ((unsigned int)f2b(acc[5]) << 16);
    pk.w = (unsigned int)f2b(acc[6]) | ((unsigned int)f2b(acc[7]) << 16);
    *(uint4*)&Xo[(size_t)node * D + c8] = pk;
}

// ---------- link predictor: 32 q/block, async UV staging, A-frags built in registers ----------
// r8 structure (best: 94.6 us) with cheap truncating product in the hot loop.
__global__ __launch_bounds__(256) void k_linkpred(const int* __restrict__ u, const int* __restrict__ v,
                                                  const unsigned short* __restrict__ X16,
                                                  const unsigned short* __restrict__ Bpack,
                                                  const float* __restrict__ P1b,
                                                  const float* __restrict__ P2w, const float* __restrict__ P2b,
                                                  float* __restrict__ out, int Q) {
    __shared__ unsigned short UV[32 * UVPITCH];   // 33,280 B
    __shared__ float red[4][32];

    int t = threadIdx.x;
    int w = t >> 6, lane = t & 63;
    int quad = lane >> 4, lcol = lane & 15;
    int q0 = blockIdx.x * 32;

    // ---- stage 0: async gather of endpoint rows (8 q per wave, 16B/lane) ----
    for (int i = 0; i < 8; ++i) {
        int q = w * 8 + i;
        int qq = q0 + q;
        int qc = (qq < Q) ? qq : 0;
        int ua = u[qc], va = v[qc];
        const char* src = (lane < 32)
            ? (const char*)(X16 + (size_t)ua * D) + lane * 16
            : (const char*)(X16 + (size_t)va * D) + (lane - 32) * 16;
        async_ld16(src, (char*)UV + q * (UVPITCH * 2) + lane * 16);
    }
    asm volatile("s_waitcnt vmcnt(0)" ::: "memory");
    __syncthreads();

    // ---- stage 1: MFMA with register-built A-frags (truncating product) ----
    frag_cd acc[2][4];
    #pragma unroll
    for (int m = 0; m < 2; ++m)
        #pragma unroll
        for (int jn = 0; jn < 4; ++jn) acc[m][jn] = (frag_cd){0.f, 0.f, 0.f, 0.f};

    const frag_ab* bp = (const frag_ab*)Bpack;
    for (int kt = 0; kt < 8; ++kt) {
        int ko = kt * 32 + quad * 8;
        union { frag_ab f; uint4 qv; } a[2];
        #pragma unroll
        for (int m = 0; m < 2; ++m) {
            const unsigned short* base = &UV[(m * 16 + lcol) * UVPITCH];
            uint4 au = *(const uint4*)(base + ko);
            uint4 av = *(const uint4*)(base + 256 + ko);
            a[m].qv.x = bmul2t(au.x, av.x);
            a[m].qv.y = bmul2t(au.y, av.y);
            a[m].qv.z = bmul2t(au.z, av.z);
            a[m].qv.w = bmul2t(au.w, av.w);
        }
        #pragma unroll
        for (int jn = 0; jn < 4; ++jn) {
            frag_ab b = bp[((w * 4 + jn) * 8 + kt) * 64 + lane];
            acc[0][jn] = __builtin_amdgcn_mfma_f32_16x16x32_bf16(a[0].f, b, acc[0][jn], 0, 0, 0);
            acc[1][jn] = __builtin_amdgcn_mfma_f32_16x16x32_bf16(a[1].f, b, acc[1][jn], 0, 0, 0);
        }
    }

    // ---- epilogue: relu(H+b1) . P2w, partial over this wave's 4 ntiles ----
    float part[2][4] = {{0.f,0.f,0.f,0.f},{0.f,0.f,0.f,0.f}};
    #pragma unroll
    for (int jn = 0; jn < 4; ++jn) {
        int col = (w * 4 + jn) * 16 + lcol;
        float bb = P1b[col];
        float pw = P2w[col];
        #pragma unroll
        for (int m = 0; m < 2; ++m)
            #pragma unroll
            for (int r = 0; r < 4; ++r)
                part[m][r] = fmaf(fmaxf(acc[m][jn][r] + bb, 0.f), pw, part[m][r]);
    }
    #pragma unroll
    for (int m = 0; m < 2; ++m)
        #pragma unroll
        for (int r = 0; r < 4; ++r) {
            float s = part[m][r];
            s += __shfl_down(s, 8);
            s += __shfl_down(s, 4);
            s += __shfl_down(s, 2);
            s += __shfl_down(s, 1);
            part[m][r] = s;
        }
    if (lcol == 0) {
        #pragma unroll
        for (int m = 0; m < 2; ++m)
            #pragma unroll
            for (int r = 0; r < 4; ++r)
                red[w][m * 16 + quad * 4 + r] = part[m][r];
    }
    __syncthreads();

    if (t < 32) {
        int qq = q0 + t;
        if (qq < Q) {
            float s = red[0][t] + red[1][t] + red[2][t] + red[3][t] + P2b[0];
            out[qq] = 1.0f / (1.0f + expf(-s));
        }
    }
}

extern "C" void kernel_launch(void* const* d_in, const int* in_sizes, int n_in,
                              void* d_out, int out_size, void* d_ws, size_t ws_size,
                              hipStream_t stream) {
    const int*   edge_index = (const int*)d_in[0];
    const int*   edges      = (const int*)d_in[1];
    const float* emb        = (const float*)d_in[2];
    const float* W1         = (const float*)d_in[3];
    const float* b1         = (const float*)d_in[4];
    const float* W2         = (const float*)d_in[5];
    const float* b2         = (const float*)d_in[6];
    const float* P1w        = (const float*)d_in[7];
    const float* P1b        = (const float*)d_in[8];
    const float* P2w        = (const float*)d_in[9];
    const float* P2b        = (const float*)d_in[10];

    int E  = in_sizes[0] / 2;
    int Q  = in_sizes[1] / 2;
    int Nn = in_sizes[2] / D;

    const int* rowp = edge_index;
    const int* colp = edge_index + E;
    const int* uq   = edges;
    const int* vq   = edges + Q;
    float* out = (float*)d_out;

    // ---- workspace layout ----
    char* ws = (char*)d_ws;
    size_t off = 0;
    auto alloc = [&](size_t bytes) -> char* {
        char* p = ws + off;
        off = (off + bytes + 255) & ~(size_t)255;
        return p;
    };
    float*          dinv   = (float*)alloc((size_t)Nn * 4);
    int*            rowptr = (int*)  alloc(((size_t)Nn + 1) * 4);
    int*            ebuf   = (int*)  alloc((size_t)E * 4);
    unsigned short* BpW1   = (unsigned short*)alloc(65536 * 2);
    unsigned short* BpW2   = (unsigned short*)alloc(65536 * 2);
    unsigned short* BpP1   = (unsigned short*)alloc(65536 * 2);
    unsigned short* hbuf   = (unsigned short*)alloc((size_t)Nn * D * 2);  // bf16
    unsigned short* xbuf   = (unsigned short*)alloc((size_t)Nn * D * 2);  // bf16

    // CSR temporaries aliased into xbuf (dead until first k_agg writes it)
    int* degi  = (int*)xbuf;
    int* fill  = degi + Nn;
    int* bsums = degi + 2 * Nn;

    int nb;
    int nscan = (Nn + SCAN_CHUNK - 1) / SCAN_CHUNK;

    // CSR build
    nb = (2 * Nn + 255) / 256; k_zero_int<<<nb, 256, 0, stream>>>(degi, 2 * Nn);
    nb = (E + 255) / 256;      k_count_int<<<nb, 256, 0, stream>>>(rowp, degi, E);
    k_scan_block<<<nscan, 256, 0, stream>>>(degi, rowptr, bsums, Nn);
    k_scan_bsums<<<1, 256, 0, stream>>>(bsums, nscan);
    nb = (Nn + 255) / 256;     k_scan_add_dinv<<<nb, 256, 0, stream>>>(rowptr, bsums, degi, dinv, Nn, E);
    nb = (E + 255) / 256;      k_bucket<<<nb, 256, 0, stream>>>(rowp, colp, rowptr, fill, ebuf, E);

    // pack all three weights for MFMA B operand (one launch)
    k_packB3<<<768, 256, 0, stream>>>(W1, W2, P1w, BpW1, BpW2, BpP1);

    // conv1: h = emb @ W1 (MFMA, fp32 A) ; x1 = relu(norm-agg(h) + b1)  [bf16]
    nb = (Nn + 31) / 32; k_gemm_mfma<<<nb, 256, 0, stream>>>((const void*)emb, 1, BpW1, hbuf, Nn);
    nb = (Nn + 7) / 8;   k_agg<<<nb, 256, 0, stream>>>(hbuf, rowptr, ebuf, dinv, b1, xbuf, Nn, 1);

    // conv2: h = x1 @ W2 (MFMA, bf16 A) ; x2 = norm-agg(h) + b2          [bf16]
    nb = (Nn + 31) / 32; k_gemm_mfma<<<nb, 256, 0, stream>>>((const void*)xbuf, 0, BpW2, hbuf, Nn);
    nb = (Nn + 7) / 8;   k_agg<<<nb, 256, 0, stream>>>(hbuf, rowptr, ebuf, dinv, b2, xbuf, Nn, 0);

    // link predictor (r8 structure + truncating product)
    nb = (Q + 31) / 32;  k_linkpred<<<nb, 256, 0, stream>>>(uq, vq, xbuf, BpP1, P1b, P2w, P2b, out, Q);
}